// Round 7
// baseline (137.709 us; speedup 1.0000x reference)
//
#include <hip/hip_runtime.h>

#define SRC_LEN 256
#define TRG_LEN 256
#define BATCH   32
#define HID     512
#define ATT     128
#define CSCALE  2.885390081777927f   // 2*log2(e): exp2(CSCALE*x) == exp(2x)

typedef float  f32x4  __attribute__((ext_vector_type(4)));
typedef short  bf16x8 __attribute__((ext_vector_type(8)));

// manual RNE fp32->bf16 (inputs are finite normals; NaN path not needed)
__device__ inline unsigned short bfr(float x) {
    unsigned u = __builtin_bit_cast(unsigned, x);
    return (unsigned short)((u + 0x7fffu + ((u >> 16) & 1u)) >> 16);
}
__device__ inline unsigned pk2(float a, float b) {
    return (unsigned)bfr(a) | ((unsigned)bfr(b) << 16);
}

// ---------------------------------------------------------------------------
// MFMA projection — frozen at the R3/R6-measured-best version (coalesced LDS
// staging of both operands, dbuf). R5's A/B test showed per-k-step divergent
// W loads cost +14.5 us; do not reintroduce.
// ---------------------------------------------------------------------------
__global__ __launch_bounds__(256) void proj_mfma(
    const float* __restrict__ dec_out, const float* __restrict__ enc_outs,
    const float* __restrict__ W_s, const float* __restrict__ W_t,
    const float* __restrict__ b_t,
    float* __restrict__ encE, float* __restrict__ decD)
{
    __shared__ __align__(16) char smem[49152];
    char* aLb = smem;            // [2][64 rows][64 k] bf16 = 2 x 8192 B
    char* bLb = smem + 16384;    // [2][128 rows][64 k] bf16 = 2 x 16384 B

    const int tid   = threadIdx.x;
    const int blk   = blockIdx.x;
    const bool isDec = blk >= 128;
    const int bb    = blk & 31;
    const int r0    = ((isDec ? blk - 128 : blk) >> 5) * 64;  // s0 or t0
    const float* __restrict__ in = isDec ? dec_out : enc_outs;
    const float* __restrict__ W  = isDec ? W_t : W_s;

    const int lane   = tid & 63;
    const int w      = tid >> 6;
    const int woff_m = (w >> 1) * 32;
    const int woff_n = (w & 1) * 64;
    const int q      = lane >> 4;
    const int l15    = lane & 15;
    const int l7     = lane & 7;

    const int am  = tid >> 2, akq = tid & 3;   // A: row am (0..63), 16-k seg
    const int wn  = tid >> 1, wkh = tid & 1;   // W: row wn (0..127), 32-k half
    const float* aGp = in + ((size_t)(r0 + am) * BATCH + bb) * HID + akq * 16;
    const float* wGp = W + (size_t)wn * HID + wkh * 32;

    float4 aR[4];
    float4 wR[8];

    f32x4 acc[2][4];
    #pragma unroll
    for (int mi = 0; mi < 2; ++mi)
        #pragma unroll
        for (int ni = 0; ni < 4; ++ni) acc[mi][ni] = (f32x4)0.0f;

    #define LOADG(c)                                                     \
        {                                                                \
            _Pragma("unroll")                                            \
            for (int i = 0; i < 4; ++i)                                  \
                aR[i] = *(const float4*)(aGp + (c) * 64 + i * 4);        \
            _Pragma("unroll")                                            \
            for (int i = 0; i < 8; ++i)                                  \
                wR[i] = *(const float4*)(wGp + (c) * 64 + i * 4);        \
        }

    #define STORES(buf)                                                  \
        {                                                                \
            char* ab = aLb + (buf) * 8192;                               \
            _Pragma("unroll")                                            \
            for (int h = 0; h < 2; ++h) {                                \
                uint4 pk;                                                \
                float4 f0 = aR[2 * h], f1 = aR[2 * h + 1];               \
                pk.x = pk2(f0.x, f0.y); pk.y = pk2(f0.z, f0.w);          \
                pk.z = pk2(f1.x, f1.y); pk.w = pk2(f1.z, f1.w);          \
                int g = akq * 2 + h;                                     \
                *(uint4*)(ab + am * 128 + ((g ^ (am & 7)) * 16)) = pk;   \
            }                                                            \
            char* bp = bLb + (buf) * 16384;                              \
            _Pragma("unroll")                                            \
            for (int h = 0; h < 4; ++h) {                                \
                uint4 pk;                                                \
                float4 f0 = wR[2 * h], f1 = wR[2 * h + 1];               \
                pk.x = pk2(f0.x, f0.y); pk.y = pk2(f0.z, f0.w);          \
                pk.z = pk2(f1.x, f1.y); pk.w = pk2(f1.z, f1.w);          \
                int g = wkh * 4 + h;                                     \
                *(uint4*)(bp + wn * 128 + ((g ^ (wn & 7)) * 16)) = pk;   \
            }                                                            \
        }

    LOADG(0);
    STORES(0);
    __syncthreads();

    for (int c = 0; c < 8; ++c) {
        if (c < 7) LOADG(c + 1);
        const char* ab = aLb + (c & 1) * 8192;
        const char* bp = bLb + (c & 1) * 16384;
        #pragma unroll
        for (int s = 0; s < 2; ++s) {
            bf16x8 af[2], bfv[4];
            const int sw = ((s * 4 + q) ^ l7) * 16;
            #pragma unroll
            for (int mi = 0; mi < 2; ++mi)
                af[mi] = *(const bf16x8*)(ab + (woff_m + mi * 16 + l15) * 128 + sw);
            #pragma unroll
            for (int ni = 0; ni < 4; ++ni)
                bfv[ni] = *(const bf16x8*)(bp + (woff_n + ni * 16 + l15) * 128 + sw);
            #pragma unroll
            for (int mi = 0; mi < 2; ++mi)
                #pragma unroll
                for (int ni = 0; ni < 4; ++ni)
                    acc[mi][ni] = __builtin_amdgcn_mfma_f32_16x16x32_bf16(
                        af[mi], bfv[ni], acc[mi][ni], 0, 0, 0);
        }
        if (c < 7) STORES((c + 1) & 1);
        __syncthreads();
    }

    if (!isDec) {
        // E' = exp(-2*enc_att), transposed store via padded LDS (stride 129)
        float* T = (float*)smem;
        #pragma unroll
        for (int mi = 0; mi < 2; ++mi)
            #pragma unroll
            for (int ni = 0; ni < 4; ++ni)
                #pragma unroll
                for (int r = 0; r < 4; ++r) {
                    const int ml = woff_m + mi * 16 + q * 4 + r;
                    const int nl = woff_n + ni * 16 + l15;
                    T[ml * 129 + nl] = __builtin_amdgcn_exp2f(-CSCALE * acc[mi][ni][r]);
                }
        __syncthreads();
        const int m  = tid & 63;
        const int n0 = tid >> 6;
        #pragma unroll
        for (int p = 0; p < 32; ++p) {
            const int n = n0 + p * 4;
            encE[((size_t)(bb * ATT + n)) * SRC_LEN + r0 + m] = T[m * 129 + n];
        }
    } else {
        // D = exp(+2*(dec_att + b_t)), natural [t][b][a] store
        float bt[4];
        #pragma unroll
        for (int ni = 0; ni < 4; ++ni) bt[ni] = b_t[woff_n + ni * 16 + l15];
        #pragma unroll
        for (int mi = 0; mi < 2; ++mi)
            #pragma unroll
            for (int ni = 0; ni < 4; ++ni)
                #pragma unroll
                for (int r = 0; r < 4; ++r) {
                    const int ml = woff_m + mi * 16 + q * 4 + r;
                    const int nl = woff_n + ni * 16 + l15;
                    decD[((size_t)(r0 + ml) * BATCH + bb) * ATT + nl] =
                        __builtin_amdgcn_exp2f(CSCALE * (acc[mi][ni][r] + bt[ni]));
                }
    }
    #undef LOADG
    #undef STORES
}

// ---------------------------------------------------------------------------
// Score v5. Identity: sum_a v_a*E_a/(E_a+D_a) over a 4-a group
//   = num/den with x_i = E_i+D_i, n_i = v_i*E_i:
//   den = x0*x1*x2*x3,  num = (n0*x1+n1*x0)*x2*x3 + (n2*x3+n3*x2)*x0*x1.
// One v_rcp per 4 elements (was 1/element). Trans pipe measured ~16cy/wave64
// (R1/R3 calibration) was the binding pipe: per g-iter 328cy -> 184cy.
// D,v stay in LDS (R6 A/B: LDS broadcast beats uniform global by ~8us).
// E register-prefetched one g-iter ahead. Grid (64,32), 100% occupancy.
// ---------------------------------------------------------------------------
__global__ __launch_bounds__(256) void score_kernel(
    const float* __restrict__ encE, const float* __restrict__ decD,
    const float* __restrict__ v_a, float* __restrict__ out)
{
    __shared__ float dS[4 * ATT];
    __shared__ float vS[ATT];
    __shared__ float sumvS;

    const int tid = threadIdx.x;
    const int t0  = blockIdx.x * 4;
    const int b   = blockIdx.y;

    if (tid < 128) {
        const int tt = tid >> 5, a4 = (tid & 31) * 4;
        *(float4*)(dS + tt * ATT + a4) =
            *(const float4*)(decD + ((size_t)(t0 + tt) * BATCH + b) * ATT + a4);
    } else if (tid < 160) {
        const int l = tid - 128;
        *(float4*)(vS + l * 4) = *(const float4*)(v_a + l * 4);
    }
    __syncthreads();
    if (tid < 64) {
        float x = vS[tid] + vS[tid + 64];
        #pragma unroll
        for (int o = 32; o > 0; o >>= 1) x += __shfl_down(x, o);
        if (tid == 0) sumvS = x;
    }
    __syncthreads();

    float acc0 = 0.f, acc1 = 0.f, acc2 = 0.f, acc3 = 0.f;
    const float* __restrict__ ep = encE + (size_t)b * ATT * SRC_LEN + tid;

    float4 E;
    E.x = ep[0 * SRC_LEN];
    E.y = ep[1 * SRC_LEN];
    E.z = ep[2 * SRC_LEN];
    E.w = ep[3 * SRC_LEN];

    #pragma unroll 4
    for (int g = 0; g < 32; ++g) {
        float4 En = E;
        if (g < 31) {
            const float* p = ep + (size_t)(g + 1) * 4 * SRC_LEN;
            En.x = p[0 * SRC_LEN];
            En.y = p[1 * SRC_LEN];
            En.z = p[2 * SRC_LEN];
            En.w = p[3 * SRC_LEN];
        }
        const float4 vv = *(const float4*)(vS + g * 4);
        const float n0 = vv.x * E.x, n1 = vv.y * E.y;
        const float n2 = vv.z * E.z, n3 = vv.w * E.w;

        #define TSTEP(ACC, DBASE)                                          \
        {                                                                  \
            const float4 d = *(const float4*)(DBASE + g * 4);              \
            const float x0 = E.x + d.x, x1 = E.y + d.y;                    \
            const float x2 = E.z + d.z, x3 = E.w + d.w;                    \
            const float a01 = x0 * x1, a23 = x2 * x3;                      \
            const float den = a01 * a23;                                   \
            const float m01 = fmaf(n0, x1, n1 * x0);                       \
            const float m23 = fmaf(n2, x3, n3 * x2);                       \
            const float num = fmaf(m01, a23, m23 * a01);                   \
            ACC = fmaf(num, __builtin_amdgcn_rcpf(den), ACC);              \
        }
        TSTEP(acc0, dS + 0 * ATT)
        TSTEP(acc1, dS + 1 * ATT)
        TSTEP(acc2, dS + 2 * ATT)
        TSTEP(acc3, dS + 3 * ATT)
        #undef TSTEP
        E = En;
    }

    const float sv = sumvS;
    out[((size_t)(t0 + 0) * BATCH + b) * SRC_LEN + tid] = sv - 2.0f * acc0;
    out[((size_t)(t0 + 1) * BATCH + b) * SRC_LEN + tid] = sv - 2.0f * acc1;
    out[((size_t)(t0 + 2) * BATCH + b) * SRC_LEN + tid] = sv - 2.0f * acc2;
    out[((size_t)(t0 + 3) * BATCH + b) * SRC_LEN + tid] = sv - 2.0f * acc3;
}

extern "C" void kernel_launch(void* const* d_in, const int* in_sizes, int n_in,
                              void* d_out, int out_size, void* d_ws, size_t ws_size,
                              hipStream_t stream) {
    const float* dec_out  = (const float*)d_in[0];
    const float* enc_outs = (const float*)d_in[1];
    const float* W_s      = (const float*)d_in[2];
    const float* W_t      = (const float*)d_in[3];
    const float* b_t      = (const float*)d_in[4];
    const float* v_a      = (const float*)d_in[5];
    float* out = (float*)d_out;

    float* encE = (float*)d_ws;                              // B*A*S = 4 MB : exp(-2*enc_att)
    float* decD = encE + (size_t)BATCH * ATT * SRC_LEN;      // T*B*A = 4 MB : exp(+2*dec_att)

    proj_mfma<<<256, 256, 0, stream>>>(dec_out, enc_outs, W_s, W_t, b_t, encE, decD);

    dim3 g3(TRG_LEN / 4, BATCH);
    score_kernel<<<g3, 256, 0, stream>>>(encE, decD, v_a, out);
}

// Round 8
// 124.220 us; speedup vs baseline: 1.1086x; 1.1086x over previous
//
#include <hip/hip_runtime.h>

#define SRC_LEN 256
#define TRG_LEN 256
#define BATCH   32
#define HID     512
#define ATT     128
#define CSCALE  2.885390081777927f   // 2*log2(e): exp2(CSCALE*x) == exp(2x)

typedef float  f32x4  __attribute__((ext_vector_type(4)));
typedef short  bf16x8 __attribute__((ext_vector_type(8)));

// manual RNE fp32->bf16 (inputs are finite normals; NaN path not needed)
__device__ inline unsigned short bfr(float x) {
    unsigned u = __builtin_bit_cast(unsigned, x);
    return (unsigned short)((u + 0x7fffu + ((u >> 16) & 1u)) >> 16);
}
__device__ inline unsigned pk2(float a, float b) {
    return (unsigned)bfr(a) | ((unsigned)bfr(b) << 16);
}

// ---------------------------------------------------------------------------
// MFMA projection — compute structure frozen at the R3/R6-measured-best
// version (coalesced LDS staging of both operands, dbuf; R5 A/B: divergent
// per-k W loads cost +14.5 us, do not reintroduce).
// R7 change: enc epilogue stores encE in [b][a>>2][s][4] layout so the score
// kernel reads its 4-a rational group as ONE coalesced dwordx4 per lane.
// dec: D = exp(+2*(dec_att + b_t)) as [t][b][a], unchanged.
// ---------------------------------------------------------------------------
__global__ __launch_bounds__(256) void proj_mfma(
    const float* __restrict__ dec_out, const float* __restrict__ enc_outs,
    const float* __restrict__ W_s, const float* __restrict__ W_t,
    const float* __restrict__ b_t,
    float* __restrict__ encE, float* __restrict__ decD)
{
    __shared__ __align__(16) char smem[49152];
    char* aLb = smem;            // [2][64 rows][64 k] bf16 = 2 x 8192 B
    char* bLb = smem + 16384;    // [2][128 rows][64 k] bf16 = 2 x 16384 B

    const int tid   = threadIdx.x;
    const int blk   = blockIdx.x;
    const bool isDec = blk >= 128;
    const int bb    = blk & 31;
    const int r0    = ((isDec ? blk - 128 : blk) >> 5) * 64;  // s0 or t0
    const float* __restrict__ in = isDec ? dec_out : enc_outs;
    const float* __restrict__ W  = isDec ? W_t : W_s;

    const int lane   = tid & 63;
    const int w      = tid >> 6;
    const int woff_m = (w >> 1) * 32;
    const int woff_n = (w & 1) * 64;
    const int q      = lane >> 4;
    const int l15    = lane & 15;
    const int l7     = lane & 7;

    const int am  = tid >> 2, akq = tid & 3;   // A: row am (0..63), 16-k seg
    const int wn  = tid >> 1, wkh = tid & 1;   // W: row wn (0..127), 32-k half
    const float* aGp = in + ((size_t)(r0 + am) * BATCH + bb) * HID + akq * 16;
    const float* wGp = W + (size_t)wn * HID + wkh * 32;

    float4 aR[4];
    float4 wR[8];

    f32x4 acc[2][4];
    #pragma unroll
    for (int mi = 0; mi < 2; ++mi)
        #pragma unroll
        for (int ni = 0; ni < 4; ++ni) acc[mi][ni] = (f32x4)0.0f;

    #define LOADG(c)                                                     \
        {                                                                \
            _Pragma("unroll")                                            \
            for (int i = 0; i < 4; ++i)                                  \
                aR[i] = *(const float4*)(aGp + (c) * 64 + i * 4);        \
            _Pragma("unroll")                                            \
            for (int i = 0; i < 8; ++i)                                  \
                wR[i] = *(const float4*)(wGp + (c) * 64 + i * 4);        \
        }

    #define STORES(buf)                                                  \
        {                                                                \
            char* ab = aLb + (buf) * 8192;                               \
            _Pragma("unroll")                                            \
            for (int h = 0; h < 2; ++h) {                                \
                uint4 pk;                                                \
                float4 f0 = aR[2 * h], f1 = aR[2 * h + 1];               \
                pk.x = pk2(f0.x, f0.y); pk.y = pk2(f0.z, f0.w);          \
                pk.z = pk2(f1.x, f1.y); pk.w = pk2(f1.z, f1.w);          \
                int g = akq * 2 + h;                                     \
                *(uint4*)(ab + am * 128 + ((g ^ (am & 7)) * 16)) = pk;   \
            }                                                            \
            char* bp = bLb + (buf) * 16384;                              \
            _Pragma("unroll")                                            \
            for (int h = 0; h < 4; ++h) {                                \
                uint4 pk;                                                \
                float4 f0 = wR[2 * h], f1 = wR[2 * h + 1];               \
                pk.x = pk2(f0.x, f0.y); pk.y = pk2(f0.z, f0.w);          \
                pk.z = pk2(f1.x, f1.y); pk.w = pk2(f1.z, f1.w);          \
                int g = wkh * 4 + h;                                     \
                *(uint4*)(bp + wn * 128 + ((g ^ (wn & 7)) * 16)) = pk;   \
            }                                                            \
        }

    LOADG(0);
    STORES(0);
    __syncthreads();

    for (int c = 0; c < 8; ++c) {
        if (c < 7) LOADG(c + 1);
        const char* ab = aLb + (c & 1) * 8192;
        const char* bp = bLb + (c & 1) * 16384;
        #pragma unroll
        for (int s = 0; s < 2; ++s) {
            bf16x8 af[2], bfv[4];
            const int sw = ((s * 4 + q) ^ l7) * 16;
            #pragma unroll
            for (int mi = 0; mi < 2; ++mi)
                af[mi] = *(const bf16x8*)(ab + (woff_m + mi * 16 + l15) * 128 + sw);
            #pragma unroll
            for (int ni = 0; ni < 4; ++ni)
                bfv[ni] = *(const bf16x8*)(bp + (woff_n + ni * 16 + l15) * 128 + sw);
            #pragma unroll
            for (int mi = 0; mi < 2; ++mi)
                #pragma unroll
                for (int ni = 0; ni < 4; ++ni)
                    acc[mi][ni] = __builtin_amdgcn_mfma_f32_16x16x32_bf16(
                        af[mi], bfv[ni], acc[mi][ni], 0, 0, 0);
        }
        if (c < 7) STORES((c + 1) & 1);
        __syncthreads();
    }

    if (!isDec) {
        // E' = exp(-2*enc_att) -> LDS transpose (stride 132: float4-aligned
        // rows, bank-rotation by 4 per m keeps writes/reads conflict-free or
        // 2-way), then [b][gq][s][4] store: one coalesced float4 per lane.
        float* T = (float*)smem;
        #pragma unroll
        for (int mi = 0; mi < 2; ++mi)
            #pragma unroll
            for (int ni = 0; ni < 4; ++ni)
                #pragma unroll
                for (int r = 0; r < 4; ++r) {
                    const int ml = woff_m + mi * 16 + q * 4 + r;
                    const int nl = woff_n + ni * 16 + l15;
                    T[ml * 132 + nl] = __builtin_amdgcn_exp2f(-CSCALE * acc[mi][ni][r]);
                }
        __syncthreads();
        {
            const int m  = tid & 63;     // s-local
            const int g0 = tid >> 6;     // 0..3
            #pragma unroll
            for (int p = 0; p < 8; ++p) {
                const int gq = g0 + p * 4;          // a-quad 0..31
                float4 v = *(const float4*)(T + m * 132 + gq * 4);
                *(float4*)(encE + (((size_t)bb * 32 + gq) * SRC_LEN + r0 + m) * 4) = v;
            }
        }
    } else {
        // D = exp(+2*(dec_att + b_t)), natural [t][b][a] store
        float bt[4];
        #pragma unroll
        for (int ni = 0; ni < 4; ++ni) bt[ni] = b_t[woff_n + ni * 16 + l15];
        #pragma unroll
        for (int mi = 0; mi < 2; ++mi)
            #pragma unroll
            for (int ni = 0; ni < 4; ++ni)
                #pragma unroll
                for (int r = 0; r < 4; ++r) {
                    const int ml = woff_m + mi * 16 + q * 4 + r;
                    const int nl = woff_n + ni * 16 + l15;
                    decD[((size_t)(r0 + ml) * BATCH + bb) * ATT + nl] =
                        __builtin_amdgcn_exp2f(CSCALE * (acc[mi][ni][r] + bt[ni]));
                }
    }
    #undef LOADG
    #undef STORES
}

// ---------------------------------------------------------------------------
// Score v6. Same 4-term rational as v5 (validated: absmax 7.8e-3):
//   sum_a v_a*E_a/(E_a+D_a) over a quad = num/den, 1 rcp per 4 elements.
// R7 diagnosis: v5 lost ~2x to instruction bloat (4 strided E-loads + 64-bit
// address bumps + runtime `g<31` branch + float4 copy chains). v6: encE is
// [b][gq][s][4] so E is ONE coalesced dwordx4 per g; loop fully unrolled,
// no branch, no manual prefetch (compiler hoists the independent loads).
// D,v stay in LDS broadcast (R6 A/B: beats uniform global by ~8 us).
// ---------------------------------------------------------------------------
__global__ __launch_bounds__(256) void score_kernel(
    const float* __restrict__ encE, const float* __restrict__ decD,
    const float* __restrict__ v_a, float* __restrict__ out)
{
    __shared__ float dS[4 * ATT];
    __shared__ float vS[ATT];
    __shared__ float sumvS;

    const int tid = threadIdx.x;
    const int t0  = blockIdx.x * 4;
    const int b   = blockIdx.y;

    if (tid < 128) {
        const int tt = tid >> 5, a4 = (tid & 31) * 4;
        *(float4*)(dS + tt * ATT + a4) =
            *(const float4*)(decD + ((size_t)(t0 + tt) * BATCH + b) * ATT + a4);
    } else if (tid < 160) {
        const int l = tid - 128;
        *(float4*)(vS + l * 4) = *(const float4*)(v_a + l * 4);
    }
    __syncthreads();
    if (tid < 64) {
        float x = vS[tid] + vS[tid + 64];
        #pragma unroll
        for (int o = 32; o > 0; o >>= 1) x += __shfl_down(x, o);
        if (tid == 0) sumvS = x;
    }
    __syncthreads();

    float acc0 = 0.f, acc1 = 0.f, acc2 = 0.f, acc3 = 0.f;
    // encE layout [b][gq][s][4]: lane tid = s reads 16B contiguous per gq.
    const float* __restrict__ ep = encE + ((size_t)b * 32 * SRC_LEN + tid) * 4;

    #pragma unroll
    for (int g = 0; g < 32; ++g) {
        const float4 E  = *(const float4*)(ep + (size_t)g * SRC_LEN * 4);
        const float4 vv = *(const float4*)(vS + g * 4);
        const float n0 = vv.x * E.x, n1 = vv.y * E.y;
        const float n2 = vv.z * E.z, n3 = vv.w * E.w;

        #define TSTEP(ACC, DBASE)                                          \
        {                                                                  \
            const float4 d = *(const float4*)(DBASE + g * 4);              \
            const float x0 = E.x + d.x, x1 = E.y + d.y;                    \
            const float x2 = E.z + d.z, x3 = E.w + d.w;                    \
            const float a01 = x0 * x1, a23 = x2 * x3;                      \
            const float den = a01 * a23;                                   \
            const float m01 = fmaf(n0, x1, n1 * x0);                       \
            const float m23 = fmaf(n2, x3, n3 * x2);                       \
            const float num = fmaf(m01, a23, m23 * a01);                   \
            ACC = fmaf(num, __builtin_amdgcn_rcpf(den), ACC);              \
        }
        TSTEP(acc0, dS + 0 * ATT)
        TSTEP(acc1, dS + 1 * ATT)
        TSTEP(acc2, dS + 2 * ATT)
        TSTEP(acc3, dS + 3 * ATT)
        #undef TSTEP
    }

    const float sv = sumvS;
    out[((size_t)(t0 + 0) * BATCH + b) * SRC_LEN + tid] = sv - 2.0f * acc0;
    out[((size_t)(t0 + 1) * BATCH + b) * SRC_LEN + tid] = sv - 2.0f * acc1;
    out[((size_t)(t0 + 2) * BATCH + b) * SRC_LEN + tid] = sv - 2.0f * acc2;
    out[((size_t)(t0 + 3) * BATCH + b) * SRC_LEN + tid] = sv - 2.0f * acc3;
}

extern "C" void kernel_launch(void* const* d_in, const int* in_sizes, int n_in,
                              void* d_out, int out_size, void* d_ws, size_t ws_size,
                              hipStream_t stream) {
    const float* dec_out  = (const float*)d_in[0];
    const float* enc_outs = (const float*)d_in[1];
    const float* W_s      = (const float*)d_in[2];
    const float* W_t      = (const float*)d_in[3];
    const float* b_t      = (const float*)d_in[4];
    const float* v_a      = (const float*)d_in[5];
    float* out = (float*)d_out;

    float* encE = (float*)d_ws;                              // B*32*S*4 = 4 MB : exp(-2*enc_att), [b][a>>2][s][4]
    float* decD = encE + (size_t)BATCH * ATT * SRC_LEN;      // T*B*A    = 4 MB : exp(+2*dec_att), [t][b][a]

    proj_mfma<<<256, 256, 0, stream>>>(dec_out, enc_outs, W_s, W_t, b_t, encE, decD);

    dim3 g3(TRG_LEN / 4, BATCH);
    score_kernel<<<g3, 256, 0, stream>>>(encE, decD, v_a, out);
}

// Round 9
// 115.898 us; speedup vs baseline: 1.1882x; 1.0718x over previous
//
#include <hip/hip_runtime.h>

#define SRC_LEN 256
#define TRG_LEN 256
#define BATCH   32
#define HID     512
#define ATT     128
#define CSCALE  2.885390081777927f   // 2*log2(e): exp2(CSCALE*x) == exp(2x)

typedef float  f32x4  __attribute__((ext_vector_type(4)));
typedef short  bf16x8 __attribute__((ext_vector_type(8)));

// manual RNE fp32->bf16 (inputs are finite normals; NaN path not needed)
__device__ inline unsigned short bfr(float x) {
    unsigned u = __builtin_bit_cast(unsigned, x);
    return (unsigned short)((u + 0x7fffu + ((u >> 16) & 1u)) >> 16);
}
__device__ inline unsigned pk2(float a, float b) {
    return (unsigned)bfr(a) | ((unsigned)bfr(b) << 16);
}

// ---------------------------------------------------------------------------
// MFMA projection v5: same tile (64 rows x 128 a, K=512 in 8 chunks), same
// coalesced staging and LDS swizzle as the R3/R6-validated version, but
// 512 threads/block (8 waves -> 2 waves/SIMD instead of 1). R8 ledger put
// proj at ~25-31 us vs ~2 us of pipe work: pure exposed latency at
// 1 wave/SIMD. Doubling resident waves lets MFMA/VALU/VMEM of one wave
// hide the ds_read->MFMA and global->LDS latencies of the other (m114).
// R5 lesson respected: no divergent W loads; W still staged via LDS.
// Wave w: m-rows woff_m=(w&3)*16, n-cols woff_n=(w>>2)*64 (1x4 mfma tiles).
// ---------------------------------------------------------------------------
__global__ __launch_bounds__(512) void proj_mfma(
    const float* __restrict__ dec_out, const float* __restrict__ enc_outs,
    const float* __restrict__ W_s, const float* __restrict__ W_t,
    const float* __restrict__ b_t,
    float* __restrict__ encE, float* __restrict__ decD)
{
    __shared__ __align__(16) char smem[49152];
    char* aLb = smem;            // [2][64 rows][128 B] = 16 KB
    char* bLb = smem + 16384;    // [2][128 rows][128 B] = 32 KB

    const int tid   = threadIdx.x;
    const int blk   = blockIdx.x;
    const bool isDec = blk >= 128;
    const int bb    = blk & 31;
    const int r0    = ((isDec ? blk - 128 : blk) >> 5) * 64;  // s0 or t0
    const float* __restrict__ in = isDec ? dec_out : enc_outs;
    const float* __restrict__ W  = isDec ? W_t : W_s;

    const int lane   = tid & 63;
    const int w      = tid >> 6;        // 0..7
    const int woff_m = (w & 3) * 16;
    const int woff_n = (w >> 2) * 64;
    const int q      = lane >> 4;
    const int l15    = lane & 15;
    const int l7     = lane & 7;

    // staging mapping: 512 threads; row group srow = tid>>4 (0..31), float4
    // column skc = tid&15 (64 k = 16 float4 per row-chunk). Consecutive tids
    // -> consecutive 16B segments: fully coalesced.
    const int srow = tid >> 4;
    const int skc  = tid & 15;
    const int sg   = skc >> 1, shalf = skc & 1;   // 16B LDS group, 8B half
    const float* aGp = in + ((size_t)(r0 + srow) * BATCH + bb) * HID + skc * 4;
    const float* wGp = W + (size_t)srow * HID + skc * 4;

    float4 aR[2];   // A rows srow, srow+32
    float4 wR[4];   // W rows srow + it*32

    f32x4 acc[4];
    #pragma unroll
    for (int ni = 0; ni < 4; ++ni) acc[ni] = (f32x4)0.0f;

    #define LOADG(c)                                                          \
        {                                                                     \
            _Pragma("unroll")                                                 \
            for (int it = 0; it < 2; ++it)                                    \
                aR[it] = *(const float4*)(aGp + (size_t)it * 32 * BATCH * HID \
                                          + (c) * 64);                        \
            _Pragma("unroll")                                                 \
            for (int it = 0; it < 4; ++it)                                    \
                wR[it] = *(const float4*)(wGp + (size_t)it * 32 * HID         \
                                          + (c) * 64);                        \
        }

    #define STORES(buf)                                                      \
        {                                                                    \
            char* ab = aLb + (buf) * 8192;                                   \
            _Pragma("unroll")                                                \
            for (int it = 0; it < 2; ++it) {                                 \
                const int i = srow + it * 32;                                \
                uint2 u;                                                     \
                u.x = pk2(aR[it].x, aR[it].y);                               \
                u.y = pk2(aR[it].z, aR[it].w);                               \
                *(uint2*)(ab + i * 128 + ((sg ^ (i & 7)) << 4)               \
                          + shalf * 8) = u;                                  \
            }                                                                \
            char* bp = bLb + (buf) * 16384;                                  \
            _Pragma("unroll")                                                \
            for (int it = 0; it < 4; ++it) {                                 \
                const int rw = srow + it * 32;                               \
                uint2 u;                                                     \
                u.x = pk2(wR[it].x, wR[it].y);                               \
                u.y = pk2(wR[it].z, wR[it].w);                               \
                *(uint2*)(bp + rw * 128 + ((sg ^ (rw & 7)) << 4)             \
                          + shalf * 8) = u;                                  \
            }                                                                \
        }

    LOADG(0);
    STORES(0);
    __syncthreads();

    for (int c = 0; c < 8; ++c) {
        if (c < 7) LOADG(c + 1);
        const char* ab = aLb + (c & 1) * 8192;
        const char* bp = bLb + (c & 1) * 16384;
        #pragma unroll
        for (int s = 0; s < 2; ++s) {
            const int sw = ((s * 4 + q) ^ l7) * 16;
            bf16x8 af = *(const bf16x8*)(ab + (woff_m + l15) * 128 + sw);
            bf16x8 bfv[4];
            #pragma unroll
            for (int ni = 0; ni < 4; ++ni)
                bfv[ni] = *(const bf16x8*)(bp + (woff_n + ni * 16 + l15) * 128 + sw);
            #pragma unroll
            for (int ni = 0; ni < 4; ++ni)
                acc[ni] = __builtin_amdgcn_mfma_f32_16x16x32_bf16(
                    af, bfv[ni], acc[ni], 0, 0, 0);
        }
        if (c < 7) STORES((c + 1) & 1);
        __syncthreads();
    }

    if (!isDec) {
        // E' = exp(-2*enc_att) -> LDS transpose (stride 132, float4-aligned)
        // -> [b][a>>2][s][4] store: one coalesced float4 per lane for score.
        float* T = (float*)smem;
        #pragma unroll
        for (int ni = 0; ni < 4; ++ni)
            #pragma unroll
            for (int r = 0; r < 4; ++r) {
                const int ml = woff_m + q * 4 + r;
                const int nl = woff_n + ni * 16 + l15;
                T[ml * 132 + nl] = __builtin_amdgcn_exp2f(-CSCALE * acc[ni][r]);
            }
        __syncthreads();
        {
            const int m  = tid & 63;     // s-local
            const int g0 = tid >> 6;     // 0..7
            #pragma unroll
            for (int p = 0; p < 4; ++p) {
                const int gq = g0 + p * 8;          // a-quad 0..31
                float4 v = *(const float4*)(T + m * 132 + gq * 4);
                *(float4*)(encE + (((size_t)bb * 32 + gq) * SRC_LEN + r0 + m) * 4) = v;
            }
        }
    } else {
        // D = exp(+2*(dec_att + b_t)), natural [t][b][a] store
        float bt[4];
        #pragma unroll
        for (int ni = 0; ni < 4; ++ni) bt[ni] = b_t[woff_n + ni * 16 + l15];
        #pragma unroll
        for (int ni = 0; ni < 4; ++ni)
            #pragma unroll
            for (int r = 0; r < 4; ++r) {
                const int ml = woff_m + q * 4 + r;
                const int nl = woff_n + ni * 16 + l15;
                decD[((size_t)(r0 + ml) * BATCH + bb) * ATT + nl] =
                    __builtin_amdgcn_exp2f(CSCALE * (acc[ni][r] + bt[ni]));
            }
    }
    #undef LOADG
    #undef STORES
}

// ---------------------------------------------------------------------------
// Score v6 (unchanged from R8, measured ~36.5 us): 4-term rational,
// 1 rcp per 4 elements; encE in [b][gq][s][4] -> one dwordx4 per g;
// full unroll, no branches; D,v via LDS broadcast.
// ---------------------------------------------------------------------------
__global__ __launch_bounds__(256) void score_kernel(
    const float* __restrict__ encE, const float* __restrict__ decD,
    const float* __restrict__ v_a, float* __restrict__ out)
{
    __shared__ float dS[4 * ATT];
    __shared__ float vS[ATT];
    __shared__ float sumvS;

    const int tid = threadIdx.x;
    const int t0  = blockIdx.x * 4;
    const int b   = blockIdx.y;

    if (tid < 128) {
        const int tt = tid >> 5, a4 = (tid & 31) * 4;
        *(float4*)(dS + tt * ATT + a4) =
            *(const float4*)(decD + ((size_t)(t0 + tt) * BATCH + b) * ATT + a4);
    } else if (tid < 160) {
        const int l = tid - 128;
        *(float4*)(vS + l * 4) = *(const float4*)(v_a + l * 4);
    }
    __syncthreads();
    if (tid < 64) {
        float x = vS[tid] + vS[tid + 64];
        #pragma unroll
        for (int o = 32; o > 0; o >>= 1) x += __shfl_down(x, o);
        if (tid == 0) sumvS = x;
    }
    __syncthreads();

    float acc0 = 0.f, acc1 = 0.f, acc2 = 0.f, acc3 = 0.f;
    const float* __restrict__ ep = encE + ((size_t)b * 32 * SRC_LEN + tid) * 4;

    #pragma unroll
    for (int g = 0; g < 32; ++g) {
        const float4 E  = *(const float4*)(ep + (size_t)g * SRC_LEN * 4);
        const float4 vv = *(const float4*)(vS + g * 4);
        const float n0 = vv.x * E.x, n1 = vv.y * E.y;
        const float n2 = vv.z * E.z, n3 = vv.w * E.w;

        #define TSTEP(ACC, DBASE)                                          \
        {                                                                  \
            const float4 d = *(const float4*)(DBASE + g * 4);              \
            const float x0 = E.x + d.x, x1 = E.y + d.y;                    \
            const float x2 = E.z + d.z, x3 = E.w + d.w;                    \
            const float a01 = x0 * x1, a23 = x2 * x3;                      \
            const float den = a01 * a23;                                   \
            const float m01 = fmaf(n0, x1, n1 * x0);                       \
            const float m23 = fmaf(n2, x3, n3 * x2);                       \
            const float num = fmaf(m01, a23, m23 * a01);                   \
            ACC = fmaf(num, __builtin_amdgcn_rcpf(den), ACC);              \
        }
        TSTEP(acc0, dS + 0 * ATT)
        TSTEP(acc1, dS + 1 * ATT)
        TSTEP(acc2, dS + 2 * ATT)
        TSTEP(acc3, dS + 3 * ATT)
        #undef TSTEP
    }

    const float sv = sumvS;
    out[((size_t)(t0 + 0) * BATCH + b) * SRC_LEN + tid] = sv - 2.0f * acc0;
    out[((size_t)(t0 + 1) * BATCH + b) * SRC_LEN + tid] = sv - 2.0f * acc1;
    out[((size_t)(t0 + 2) * BATCH + b) * SRC_LEN + tid] = sv - 2.0f * acc2;
    out[((size_t)(t0 + 3) * BATCH + b) * SRC_LEN + tid] = sv - 2.0f * acc3;
}

extern "C" void kernel_launch(void* const* d_in, const int* in_sizes, int n_in,
                              void* d_out, int out_size, void* d_ws, size_t ws_size,
                              hipStream_t stream) {
    const float* dec_out  = (const float*)d_in[0];
    const float* enc_outs = (const float*)d_in[1];
    const float* W_s      = (const float*)d_in[2];
    const float* W_t      = (const float*)d_in[3];
    const float* b_t      = (const float*)d_in[4];
    const float* v_a      = (const float*)d_in[5];
    float* out = (float*)d_out;

    float* encE = (float*)d_ws;                              // B*32*S*4 = 4 MB : exp(-2*enc_att), [b][a>>2][s][4]
    float* decD = encE + (size_t)BATCH * ATT * SRC_LEN;      // T*B*A    = 4 MB : exp(+2*dec_att), [t][b][a]

    proj_mfma<<<256, 512, 0, stream>>>(dec_out, enc_outs, W_s, W_t, b_t, encE, decD);

    dim3 g3(TRG_LEN / 4, BATCH);
    score_kernel<<<g3, 256, 0, stream>>>(encE, decD, v_a, out);
}